// Round 1
// 948.567 us; speedup vs baseline: 1.1792x; 1.1792x over previous
//
#include <hip/hip_runtime.h>
#include <hip/hip_bf16.h>
#include <stdint.h>

// Problem constants (fixed by setup_inputs)
#define N_TOK 32768
#define DIM   2048   // K
#define ODIM  2048   // N
#define NEXP  16

#define BM 256
#define BN 256
#define BK 64
#define NT (DIM / BK)   // 32 K-tiles

#define GLOBAL_AS __attribute__((address_space(1)))
#define LDS_AS    __attribute__((address_space(3)))

typedef short bf8_t  __attribute__((ext_vector_type(8)));  // 8 bf16 = 4 VGPRs
typedef float f4_t   __attribute__((ext_vector_type(4)));  // MFMA acc

__device__ __forceinline__ uint16_t f32_to_bf16_rne(float f) {
    uint32_t u = __float_as_uint(f);
    uint32_t r = (u + 0x7FFFu + ((u >> 16) & 1u)) >> 16;
    return (uint16_t)r;
}

// ---------------------------------------------------------------------------
// Pass 1a: x (N,K) fp32 -> bf16, same layout. Vectorized float4 -> ushort4.
// ---------------------------------------------------------------------------
__global__ void cvt_x_kernel(const float* __restrict__ x,
                             uint16_t* __restrict__ xb, int n4) {
    int i = blockIdx.x * blockDim.x + threadIdx.x;
    if (i >= n4) return;
    float4 v = ((const float4*)x)[i];
    ushort4 o;
    o.x = f32_to_bf16_rne(v.x);
    o.y = f32_to_bf16_rne(v.y);
    o.z = f32_to_bf16_rne(v.z);
    o.w = f32_to_bf16_rne(v.w);
    ((ushort4*)xb)[i] = o;
}

// ---------------------------------------------------------------------------
// Pass 1b: w (E,K,O) fp32 -> wT (E,O,K) bf16. 64x64 LDS tile transpose.
// ---------------------------------------------------------------------------
__global__ void cvt_wT_kernel(const float* __restrict__ w,
                              uint16_t* __restrict__ wT) {
    __shared__ float s[64][65];
    const int e  = blockIdx.z;
    const int o0 = blockIdx.x * 64;
    const int d0 = blockIdx.y * 64;
    const float*  we  = w  + (size_t)e * DIM * ODIM;
    uint16_t*     wTe = wT + (size_t)e * (size_t)ODIM * DIM;
    const int c  = threadIdx.x & 63;
    const int r0 = threadIdx.x >> 6;  // 0..3
#pragma unroll
    for (int r = r0; r < 64; r += 4)
        s[r][c] = we[(size_t)(d0 + r) * ODIM + (o0 + c)];
    __syncthreads();
#pragma unroll
    for (int r = r0; r < 64; r += 4)
        wTe[(size_t)(o0 + r) * DIM + (d0 + c)] = f32_to_bf16_rne(s[c][r]);
}

// ---------------------------------------------------------------------------
// Pass 2: grouped GEMM, 256x256 tile, BK=64, 8 waves (2Mx4N), 8-phase
// schedule with counted vmcnt (T3+T4), st_16x32 LDS XOR swizzle (T2),
// setprio around MFMA clusters (T5), XCD-aware block swizzle (T1).
//
// LDS (128 KiB): A[2 buf][2 half][128 row][64 k] | B[2 buf][2 half][128][64]
// Swizzle: phys_byte = logical_byte ^ (((logical_byte>>9)&1)<<5)  (involution)
// global_load_lds writes linearly -> inverse-swizzle the per-lane GLOBAL
// source address; ds_read applies the same XOR (rule 21).
//
// Phase order per K-tile: (mh,nh) = (0,0),(0,1),(1,0),(1,1).
//   A-half0 last read @p1 -> restaged @p2 (tile j+2)
//   B-half0 last read @p2 -> restaged @p3 (tile j+2)
//   A-h1/B-h1 last read @p3 -> restaged @next tile's p0 (tile j+1 -> buf^1)
// Tile-end wait: vmcnt(4) (p2+p3's 4 loads stay in flight) -> never 0 in
// steady state. Raw s_barrier only (no __syncthreads vmcnt(0) drain).
// ---------------------------------------------------------------------------
__device__ __forceinline__ void async_copy16(const uint16_t* g, uint16_t* l) {
    __builtin_amdgcn_global_load_lds((const GLOBAL_AS void*)g,
                                     (LDS_AS void*)l, 16, 0, 0);
}

#define STAGE_A(BUF, HALF, KT) do {                                           \
    const uint16_t* _g = aSrc + (size_t)(HALF) * 128 * DIM + (KT) * 64;       \
    uint16_t* _l = aDst + (BUF) * 16384 + (HALF) * 8192;                      \
    async_copy16(_g, _l);                                                     \
    async_copy16(_g + (size_t)64 * DIM, _l + 4096);                           \
} while (0)

#define STAGE_B(BUF, HALF, KT) do {                                           \
    const uint16_t* _g = bSrc + (size_t)(HALF) * 128 * DIM + (KT) * 64;       \
    uint16_t* _l = bDst + (BUF) * 16384 + (HALF) * 8192;                      \
    async_copy16(_g, _l);                                                     \
    async_copy16(_g + (size_t)64 * DIM, _l + 4096);                           \
} while (0)

#define PHASE(BUF, MH, NH, STAGE_CODE, TAIL_CODE) do {                        \
    bf8_t af[4][2], bf[2][2];                                                 \
    const uint16_t* _a = Afr + (BUF) * 16384 + (MH) * 8192;                   \
    const uint16_t* _b = Bfr + (BUF) * 16384 + (NH) * 8192;                   \
    _Pragma("unroll") for (int mi = 0; mi < 4; ++mi)                          \
        _Pragma("unroll") for (int ks = 0; ks < 2; ++ks)                      \
            af[mi][ks] = *(const bf8_t*)(_a + mi * 1024 + ks * 32);           \
    _Pragma("unroll") for (int ni = 0; ni < 2; ++ni)                          \
        _Pragma("unroll") for (int ks = 0; ks < 2; ++ks)                      \
            bf[ni][ks] = *(const bf8_t*)(_b + ni * 1024 + ks * 32);           \
    STAGE_CODE                                                                \
    __builtin_amdgcn_s_barrier();                                             \
    asm volatile("s_waitcnt lgkmcnt(0)" ::: "memory");                        \
    __builtin_amdgcn_sched_barrier(0);                                        \
    __builtin_amdgcn_s_setprio(1);                                            \
    _Pragma("unroll") for (int ks = 0; ks < 2; ++ks)                          \
        _Pragma("unroll") for (int mi = 0; mi < 4; ++mi)                      \
            _Pragma("unroll") for (int ni = 0; ni < 2; ++ni)                  \
                acc[MH][NH][mi][ni] = __builtin_amdgcn_mfma_f32_16x16x32_bf16(\
                    af[mi][ks], bf[ni][ks], acc[MH][NH][mi][ni], 0, 0, 0);    \
    __builtin_amdgcn_s_setprio(0);                                            \
    TAIL_CODE                                                                 \
    __builtin_amdgcn_s_barrier();                                             \
} while (0)

__global__ void __launch_bounds__(512, 2)
grouped_gemm_kernel(const uint16_t* __restrict__ A,
                    const uint16_t* __restrict__ BT,
                    const int* __restrict__ gsize,
                    float* __restrict__ C) {
    __shared__ __align__(16) uint16_t smem[65536];   // 128 KiB

    // T1: XCD-aware swizzle. nwg = 1024 = 8 XCDs x 128; each XCD gets 16
    // consecutive tile_m rows x all 8 tile_n (A-panel reuse in its L2).
    const int bid = blockIdx.x;
    const int wg  = (bid & 7) * 128 + (bid >> 3);
    const int tile_m = wg >> 3;           // 0..127
    const int tile_n = wg & 7;            // 0..7
    const int row0 = tile_m * BM;
    const int col0 = tile_n * BN;

    // Expert lookup (groups are multiples of BM=256: tiles never straddle).
    int e = 0, base = 0;
#pragma unroll
    for (int i = 0; i < NEXP; ++i) {
        int nx = base + gsize[i];
        if (row0 >= nx) { base = nx; e = i + 1; }
    }
    const uint16_t* Be = BT + (size_t)e * (size_t)ODIM * DIM;

    const int tid  = threadIdx.x;
    const int lane = tid & 63;
    const int wave = tid >> 6;   // 0..7
    const int wm   = wave >> 2;  // 0..1 (M)
    const int wn   = wave & 3;   // 0..3 (N)
    const int fr   = lane & 15;
    const int fq   = lane >> 4;

    // --- staging: per-thread linear LDS dest byte d0 -> inverse-swizzled
    //     logical (row, col) in the half-tile; global src gets the swizzle.
    const int d0   = wave * 1024 + lane * 16;
    const int l0   = d0 ^ (((d0 >> 9) & 1) << 5);
    const int srow = l0 >> 7;            // 0..63 (issue 1 adds 64)
    const int scol = (l0 & 127) >> 1;    // element 0..63
    const uint16_t* aSrc = A  + (size_t)(row0 + srow) * DIM + scol;
    const uint16_t* bSrc = Be + (size_t)(col0 + srow) * DIM + scol;
    uint16_t* const aDst = smem + wave * 512;            // HW adds lane*16B
    uint16_t* const bDst = smem + 32768 + wave * 512;

    // --- fragment read bases (element offsets, swizzled k)
    const int xorel = ((fr >> 2) & 1) << 4;   // row bit2 -> flip k by 16 elems
    const uint16_t* const Afr = smem + (size_t)(wm * 64 + fr) * 64
                                     + ((fq * 8) ^ xorel);
    const uint16_t* const Bfr = smem + 32768 + (size_t)(wn * 32 + fr) * 64
                                     + ((fq * 8) ^ xorel);

    f4_t acc[2][2][4][2] = {};   // [mh][nh][mi][ni]

    // Prologue: tile0 fully + tile1's h0 pair; vmcnt(4) leaves tile1-h0 in flight.
    STAGE_A(0, 0, 0); STAGE_A(0, 1, 0); STAGE_B(0, 0, 0); STAGE_B(0, 1, 0);
    STAGE_A(1, 0, 1); STAGE_B(1, 0, 1);
    asm volatile("s_waitcnt vmcnt(4)" ::: "memory");
    __builtin_amdgcn_s_barrier();

#pragma unroll 1
    for (int j = 0; j < NT; j += 2) {
        // ---- tile j (buf 0)
        PHASE(0, 0, 0, { STAGE_A(1, 1, j + 1); STAGE_B(1, 1, j + 1); }, {});
        PHASE(0, 0, 1, {}, {});
        PHASE(0, 1, 0, { if (j + 2 < NT) STAGE_A(0, 0, j + 2); }, {});
        PHASE(0, 1, 1, { if (j + 2 < NT) STAGE_B(0, 0, j + 2); },
              { if (j + 2 < NT) asm volatile("s_waitcnt vmcnt(4)" ::: "memory");
                else            asm volatile("s_waitcnt vmcnt(0)" ::: "memory"); });
        // ---- tile j+1 (buf 1)
        PHASE(1, 0, 0, { if (j + 2 < NT) { STAGE_A(0, 1, j + 2); STAGE_B(0, 1, j + 2); } }, {});
        PHASE(1, 0, 1, {}, {});
        PHASE(1, 1, 0, { if (j + 3 < NT) STAGE_A(1, 0, j + 3); }, {});
        PHASE(1, 1, 1, { if (j + 3 < NT) STAGE_B(1, 0, j + 3); },
              { if (j + 3 < NT) asm volatile("s_waitcnt vmcnt(4)" ::: "memory");
                else            asm volatile("s_waitcnt vmcnt(0)" ::: "memory"); });
    }

    // Epilogue: C/D layout col=lane&15, row=(lane>>4)*4+reg [m89/m91]
    float* Cb = C + (size_t)(row0 + wm * 64 + fq * 4) * ODIM
                  + (col0 + wn * 32 + fr);
#pragma unroll
    for (int mh = 0; mh < 2; ++mh)
#pragma unroll
        for (int nh = 0; nh < 2; ++nh)
#pragma unroll
            for (int mi = 0; mi < 4; ++mi)
#pragma unroll
                for (int ni = 0; ni < 2; ++ni)
#pragma unroll
                    for (int r = 0; r < 4; ++r)
                        Cb[(size_t)(mh * 128 + mi * 16 + r) * ODIM
                           + nh * 128 + ni * 16] = acc[mh][nh][mi][ni][r];
}

// ---------------------------------------------------------------------------
extern "C" void kernel_launch(void* const* d_in, const int* in_sizes, int n_in,
                              void* d_out, int out_size, void* d_ws, size_t ws_size,
                              hipStream_t stream) {
    const float* x  = (const float*)d_in[0];
    const float* w  = (const float*)d_in[1];
    const int*   gs = (const int*)d_in[2];
    float* out = (float*)d_out;

    // workspace: xb (N*K bf16, 128MB) | wT (E*O*K bf16, 128MB)
    uint16_t* xb = (uint16_t*)d_ws;
    uint16_t* wT = xb + (size_t)N_TOK * DIM;

    int n4 = N_TOK * DIM / 4;
    cvt_x_kernel<<<(n4 + 255) / 256, 256, 0, stream>>>(x, xb, n4);

    dim3 tg(ODIM / 64, DIM / 64, NEXP);
    cvt_wT_kernel<<<tg, 256, 0, stream>>>(w, wT);

    grouped_gemm_kernel<<<dim3((ODIM / BN) * (N_TOK / BM)), 512, 0, stream>>>(
        xb, wT, gs, out);
}

// Round 2
// 862.820 us; speedup vs baseline: 1.2963x; 1.0994x over previous
//
#include <hip/hip_runtime.h>
#include <hip/hip_bf16.h>
#include <stdint.h>

// Problem constants (fixed by setup_inputs)
#define N_TOK 32768
#define DIM   2048   // K
#define ODIM  2048   // N
#define NEXP  16

#define BM 256
#define BN 256
#define BK 64
#define NT (DIM / BK)   // 32 K-tiles

#define GLOBAL_AS __attribute__((address_space(1)))
#define LDS_AS    __attribute__((address_space(3)))

typedef short bf8_t  __attribute__((ext_vector_type(8)));  // 8 bf16 = 4 VGPRs
typedef float f4_t   __attribute__((ext_vector_type(4)));  // MFMA acc
typedef unsigned short us8_t __attribute__((ext_vector_type(8)));

__device__ __forceinline__ uint16_t f32_to_bf16_rne(float f) {
    uint32_t u = __float_as_uint(f);
    uint32_t r = (u + 0x7FFFu + ((u >> 16) & 1u)) >> 16;
    return (uint16_t)r;
}

// ---------------------------------------------------------------------------
// Pass 1a: x (N,K) fp32 -> bf16. 8 elems/thread, 16B stores, grid-stride.
// ---------------------------------------------------------------------------
__global__ void cvt_x_kernel(const float* __restrict__ x,
                             uint16_t* __restrict__ xb, int n8) {
    const int stride = gridDim.x * blockDim.x;
    for (int i = blockIdx.x * blockDim.x + threadIdx.x; i < n8; i += stride) {
        float4 a = ((const float4*)x)[2 * i];
        float4 b = ((const float4*)x)[2 * i + 1];
        us8_t o;
        o[0] = f32_to_bf16_rne(a.x); o[1] = f32_to_bf16_rne(a.y);
        o[2] = f32_to_bf16_rne(a.z); o[3] = f32_to_bf16_rne(a.w);
        o[4] = f32_to_bf16_rne(b.x); o[5] = f32_to_bf16_rne(b.y);
        o[6] = f32_to_bf16_rne(b.z); o[7] = f32_to_bf16_rne(b.w);
        ((us8_t*)xb)[i] = o;
    }
}

// ---------------------------------------------------------------------------
// Pass 1b: w (E,K,O) fp32 -> wT (E,O,K) bf16. 64x64 LDS tile transpose.
// Reads: float4, coalesced. Writes: ushort8 (16B). LDS read pattern
// bank = (8g + j + oo) % 32 -> 2-way max (free).
// ---------------------------------------------------------------------------
__global__ void cvt_wT_kernel(const float* __restrict__ w,
                              uint16_t* __restrict__ wT) {
    __shared__ float s[64][65];
    const int e  = blockIdx.z;
    const int o0 = blockIdx.x * 64;
    const int d0 = blockIdx.y * 64;
    const float*  we  = w  + (size_t)e * DIM * ODIM;
    uint16_t*     wTe = wT + (size_t)e * (size_t)ODIM * DIM;
    const int tid = threadIdx.x;
    const int c4  = (tid & 15) * 4;
    const int r0  = tid >> 4;          // 0..15
#pragma unroll
    for (int r = r0; r < 64; r += 16)
        *(float4*)&s[r][c4] =
            *(const float4*)&we[(size_t)(d0 + r) * ODIM + o0 + c4];
    __syncthreads();
    const int g   = tid & 7;           // K-chunk of 8
    const int or0 = tid >> 3;          // 0..31
#pragma unroll
    for (int oo = or0; oo < 64; oo += 32) {
        us8_t v;
#pragma unroll
        for (int j = 0; j < 8; ++j)
            v[j] = f32_to_bf16_rne(s[g * 8 + j][oo]);
        *(us8_t*)&wTe[(size_t)(o0 + oo) * DIM + d0 + g * 8] = v;
    }
}

// ---------------------------------------------------------------------------
// Pass 2: grouped GEMM, 256x256 tile, BK=64, 8 waves (2Mx4N), 8-phase
// schedule with counted vmcnt (T3+T4), setprio (T5), XCD swizzle (T1).
//
// LDS swizzle (T2), 2-bit: phys = logical ^ (bit9->bit5) ^ (bit10->bit6).
// Row stride is 128B (=32 banks), so row bits 2,3 (byte bits 9,10) are
// XORed into the 16B-slot index (byte bits 5,6): within one ds_read_b128
// the 64 lanes now cover all 8 slots x all 32 banks at the 8-access floor.
// global_load_lds writes linearly -> inverse-swizzle the per-lane GLOBAL
// source address; ds_read applies the same XOR (rule 21, involution).
//
// Fragment reads hoisted (m201 pattern): each A/B half is ds_read ONCE per
// K-tile and held in registers across the two phases that consume it:
//   p0: load af0(8)+bf0(4) -> mfma(af0,bf0)
//   p1: load bf1(4)        -> mfma(af0,bf1)
//   p2: load af1(8)        -> mfma(af1,bf0)
//   p3: (none)             -> mfma(af1,bf1)
// 24 b128/tile/wave (was 48) -> LDS-read clocks ~= MFMA clocks.
//
// Staging/vmcnt schedule unchanged from the passing round-1 kernel.
// ---------------------------------------------------------------------------
__device__ __forceinline__ void async_copy16(const uint16_t* g, uint16_t* l) {
    __builtin_amdgcn_global_load_lds((const GLOBAL_AS void*)g,
                                     (LDS_AS void*)l, 16, 0, 0);
}

#define STAGE_A(BUF, HALF, KT) do {                                           \
    const uint16_t* _g = aSrc + (size_t)(HALF) * 128 * DIM + (KT) * 64;       \
    uint16_t* _l = aDst + (BUF) * 16384 + (HALF) * 8192;                      \
    async_copy16(_g, _l);                                                     \
    async_copy16(_g + (size_t)64 * DIM, _l + 4096);                           \
} while (0)

#define STAGE_B(BUF, HALF, KT) do {                                           \
    const uint16_t* _g = bSrc + (size_t)(HALF) * 128 * DIM + (KT) * 64;       \
    uint16_t* _l = bDst + (BUF) * 16384 + (HALF) * 8192;                      \
    async_copy16(_g, _l);                                                     \
    async_copy16(_g + (size_t)64 * DIM, _l + 4096);                           \
} while (0)

// ds_read one A half (8 x b128) into dst[4][2]
#define LOAD_A(dst, BUF, MH) do {                                             \
    const uint16_t* _p = smem + (BUF) * 16384 + (MH) * 8192;                  \
    _Pragma("unroll") for (int mi = 0; mi < 4; ++mi) {                        \
        const uint16_t* _r = _p + (wm * 64 + mi * 16 + fr) * 64;              \
        dst[mi][0] = *(const bf8_t*)(_r + colk0);                             \
        dst[mi][1] = *(const bf8_t*)(_r + colk1);                             \
    }                                                                         \
} while (0)

// ds_read one B half (4 x b128) into dst[2][2]
#define LOAD_B(dst, BUF, NH) do {                                             \
    const uint16_t* _p = smem + 32768 + (BUF) * 16384 + (NH) * 8192;          \
    _Pragma("unroll") for (int ni = 0; ni < 2; ++ni) {                        \
        const uint16_t* _r = _p + (wn * 32 + ni * 16 + fr) * 64;              \
        dst[ni][0] = *(const bf8_t*)(_r + colk0);                             \
        dst[ni][1] = *(const bf8_t*)(_r + colk1);                             \
    }                                                                         \
} while (0)

#define PHASE_CORE(AF, BF, MH, NH, STAGE_CODE, TAIL_CODE) do {                \
    STAGE_CODE                                                                \
    __builtin_amdgcn_s_barrier();                                             \
    asm volatile("s_waitcnt lgkmcnt(0)" ::: "memory");                        \
    __builtin_amdgcn_sched_barrier(0);                                        \
    __builtin_amdgcn_s_setprio(1);                                            \
    _Pragma("unroll") for (int ks = 0; ks < 2; ++ks)                          \
        _Pragma("unroll") for (int mi = 0; mi < 4; ++mi)                      \
            _Pragma("unroll") for (int ni = 0; ni < 2; ++ni)                  \
                acc[MH][NH][mi][ni] = __builtin_amdgcn_mfma_f32_16x16x32_bf16(\
                    AF[mi][ks], BF[ni][ks], acc[MH][NH][mi][ni], 0, 0, 0);    \
    __builtin_amdgcn_s_setprio(0);                                            \
    TAIL_CODE                                                                 \
    __builtin_amdgcn_s_barrier();                                             \
} while (0)

__global__ void __launch_bounds__(512, 2)
grouped_gemm_kernel(const uint16_t* __restrict__ A,
                    const uint16_t* __restrict__ BT,
                    const int* __restrict__ gsize,
                    float* __restrict__ C) {
    __shared__ __align__(16) uint16_t smem[65536];   // 128 KiB

    // T1: XCD-aware swizzle. nwg = 1024 = 8 XCDs x 128.
    const int bid = blockIdx.x;
    const int wg  = (bid & 7) * 128 + (bid >> 3);
    const int tile_m = wg >> 3;           // 0..127
    const int tile_n = wg & 7;            // 0..7
    const int row0 = tile_m * BM;
    const int col0 = tile_n * BN;

    // Expert lookup (groups are multiples of BM=256: tiles never straddle).
    int e = 0, base = 0;
#pragma unroll
    for (int i = 0; i < NEXP; ++i) {
        int nx = base + gsize[i];
        if (row0 >= nx) { base = nx; e = i + 1; }
    }
    const uint16_t* Be = BT + (size_t)e * (size_t)ODIM * DIM;

    const int tid  = threadIdx.x;
    const int lane = tid & 63;
    const int wave = tid >> 6;   // 0..7
    const int wm   = wave >> 2;  // 0..1 (M)
    const int wn   = wave & 3;   // 0..3 (N)
    const int fr   = lane & 15;
    const int fq   = lane >> 4;

    // --- staging: linear LDS dest byte d0 -> inverse-swizzled logical
    //     (row,col); the global source gets the swizzle (rule 21).
    const int d0b = wave * 1024 + lane * 16;
    const int l0  = d0b ^ (((d0b >> 9) & 1) << 5) ^ (((d0b >> 10) & 1) << 6);
    const int srow = l0 >> 7;            // 0..63 (issue 1 adds 64)
    const int scol = (l0 & 127) >> 1;    // element 0..63
    const uint16_t* aSrc = A  + (size_t)(row0 + srow) * DIM + scol;
    const uint16_t* bSrc = Be + (size_t)(col0 + srow) * DIM + scol;
    uint16_t* const aDst = smem + wave * 512;            // HW adds lane*16B
    uint16_t* const bDst = smem + 32768 + wave * 512;

    // --- fragment read column offsets (elements), 2-bit XOR swizzle:
    //     flip elem bit4 (byte bit5) on row bit2, elem bit5 (byte bit6) on
    //     row bit3. row bits 2,3 == fr bits 2,3 (mi*16/ni*16 only touch >=4).
    const int xorel = (fr & 12) << 2;
    const int colk0 = (fq * 8) ^ xorel;
    const int colk1 = (fq * 8 + 32) ^ xorel;

    f4_t acc[2][2][4][2] = {};   // [mh][nh][mi][ni]

    // Prologue: tile0 fully + tile1's h0; vmcnt(4) leaves tile1-h0 in flight.
    STAGE_A(0, 0, 0); STAGE_A(0, 1, 0); STAGE_B(0, 0, 0); STAGE_B(0, 1, 0);
    STAGE_A(1, 0, 1); STAGE_B(1, 0, 1);
    asm volatile("s_waitcnt vmcnt(4)" ::: "memory");
    __builtin_amdgcn_s_barrier();

#pragma unroll 1
    for (int j = 0; j < NT; j += 2) {
        bf8_t af0[4][2], af1[4][2], bf0[2][2], bf1[2][2];
        // ---- tile j (buf 0)
        LOAD_A(af0, 0, 0); LOAD_B(bf0, 0, 0);
        PHASE_CORE(af0, bf0, 0, 0,
                   { STAGE_A(1, 1, j + 1); STAGE_B(1, 1, j + 1); }, {});
        LOAD_B(bf1, 0, 1);
        PHASE_CORE(af0, bf1, 0, 1, {}, {});
        LOAD_A(af1, 0, 1);
        PHASE_CORE(af1, bf0, 1, 0, { if (j + 2 < NT) STAGE_A(0, 0, j + 2); }, {});
        PHASE_CORE(af1, bf1, 1, 1, { if (j + 2 < NT) STAGE_B(0, 0, j + 2); },
              { if (j + 2 < NT) asm volatile("s_waitcnt vmcnt(4)" ::: "memory");
                else            asm volatile("s_waitcnt vmcnt(0)" ::: "memory"); });
        // ---- tile j+1 (buf 1)
        LOAD_A(af0, 1, 0); LOAD_B(bf0, 1, 0);
        PHASE_CORE(af0, bf0, 0, 0,
                   { if (j + 2 < NT) { STAGE_A(0, 1, j + 2); STAGE_B(0, 1, j + 2); } }, {});
        LOAD_B(bf1, 1, 1);
        PHASE_CORE(af0, bf1, 0, 1, {}, {});
        LOAD_A(af1, 1, 1);
        PHASE_CORE(af1, bf0, 1, 0, { if (j + 3 < NT) STAGE_A(1, 0, j + 3); }, {});
        PHASE_CORE(af1, bf1, 1, 1, { if (j + 3 < NT) STAGE_B(1, 0, j + 3); },
              { if (j + 3 < NT) asm volatile("s_waitcnt vmcnt(4)" ::: "memory");
                else            asm volatile("s_waitcnt vmcnt(0)" ::: "memory"); });
    }

    // Epilogue: C/D layout col=lane&15, row=(lane>>4)*4+reg [m89/m91]
    float* Cb = C + (size_t)(row0 + wm * 64 + fq * 4) * ODIM
                  + (col0 + wn * 32 + fr);
#pragma unroll
    for (int mh = 0; mh < 2; ++mh)
#pragma unroll
        for (int nh = 0; nh < 2; ++nh)
#pragma unroll
            for (int mi = 0; mi < 4; ++mi)
#pragma unroll
                for (int ni = 0; ni < 2; ++ni)
#pragma unroll
                    for (int r = 0; r < 4; ++r)
                        Cb[(size_t)(mh * 128 + mi * 16 + r) * ODIM
                           + nh * 128 + ni * 16] = acc[mh][nh][mi][ni][r];
}

// ---------------------------------------------------------------------------
extern "C" void kernel_launch(void* const* d_in, const int* in_sizes, int n_in,
                              void* d_out, int out_size, void* d_ws, size_t ws_size,
                              hipStream_t stream) {
    const float* x  = (const float*)d_in[0];
    const float* w  = (const float*)d_in[1];
    const int*   gs = (const int*)d_in[2];
    float* out = (float*)d_out;

    // workspace: xb (N*K bf16, 128MB) | wT (E*O*K bf16, 128MB)
    uint16_t* xb = (uint16_t*)d_ws;
    uint16_t* wT = xb + (size_t)N_TOK * DIM;

    int n8 = N_TOK * DIM / 8;
    cvt_x_kernel<<<4096, 256, 0, stream>>>(x, xb, n8);

    dim3 tg(ODIM / 64, DIM / 64, NEXP);
    cvt_wT_kernel<<<tg, 256, 0, stream>>>(w, wT);

    grouped_gemm_kernel<<<dim3((ODIM / BN) * (N_TOK / BM)), 512, 0, stream>>>(
        xb, wT, gs, out);
}

// Round 3
// 848.315 us; speedup vs baseline: 1.3185x; 1.0171x over previous
//
#include <hip/hip_runtime.h>
#include <hip/hip_bf16.h>
#include <stdint.h>

// Problem constants (fixed by setup_inputs)
#define N_TOK 32768
#define DIM   2048   // K
#define ODIM  2048   // N
#define NEXP  16

#define BM 256
#define BN 256
#define BK 64
#define NT (DIM / BK)   // 32 K-tiles

#define GLOBAL_AS __attribute__((address_space(1)))
#define LDS_AS    __attribute__((address_space(3)))

typedef short bf8_t  __attribute__((ext_vector_type(8)));  // 8 bf16 = 4 VGPRs
typedef float f4_t   __attribute__((ext_vector_type(4)));  // MFMA acc
typedef unsigned short us8_t __attribute__((ext_vector_type(8)));

__device__ __forceinline__ uint16_t f32_to_bf16_rne(float f) {
    uint32_t u = __float_as_uint(f);
    uint32_t r = (u + 0x7FFFu + ((u >> 16) & 1u)) >> 16;
    return (uint16_t)r;
}

// ---------------------------------------------------------------------------
// Pass 1a: x (N,K) fp32 -> bf16. 8 elems/thread, 16B stores, grid-stride.
// ---------------------------------------------------------------------------
__global__ void cvt_x_kernel(const float* __restrict__ x,
                             uint16_t* __restrict__ xb, int n8) {
    const int stride = gridDim.x * blockDim.x;
    for (int i = blockIdx.x * blockDim.x + threadIdx.x; i < n8; i += stride) {
        float4 a = ((const float4*)x)[2 * i];
        float4 b = ((const float4*)x)[2 * i + 1];
        us8_t o;
        o[0] = f32_to_bf16_rne(a.x); o[1] = f32_to_bf16_rne(a.y);
        o[2] = f32_to_bf16_rne(a.z); o[3] = f32_to_bf16_rne(a.w);
        o[4] = f32_to_bf16_rne(b.x); o[5] = f32_to_bf16_rne(b.y);
        o[6] = f32_to_bf16_rne(b.z); o[7] = f32_to_bf16_rne(b.w);
        ((us8_t*)xb)[i] = o;
    }
}

// ---------------------------------------------------------------------------
// Pass 1b: w (E,K,O) fp32 -> wT (E,O,K) bf16. 64x64 LDS tile transpose.
// ---------------------------------------------------------------------------
__global__ void cvt_wT_kernel(const float* __restrict__ w,
                              uint16_t* __restrict__ wT) {
    __shared__ float s[64][65];
    const int e  = blockIdx.z;
    const int o0 = blockIdx.x * 64;
    const int d0 = blockIdx.y * 64;
    const float*  we  = w  + (size_t)e * DIM * ODIM;
    uint16_t*     wTe = wT + (size_t)e * (size_t)ODIM * DIM;
    const int tid = threadIdx.x;
    const int c4  = (tid & 15) * 4;
    const int r0  = tid >> 4;          // 0..15
#pragma unroll
    for (int r = r0; r < 64; r += 16)
        *(float4*)&s[r][c4] =
            *(const float4*)&we[(size_t)(d0 + r) * ODIM + o0 + c4];
    __syncthreads();
    const int g   = tid & 7;           // K-chunk of 8
    const int or0 = tid >> 3;          // 0..31
#pragma unroll
    for (int oo = or0; oo < 64; oo += 32) {
        us8_t v;
#pragma unroll
        for (int j = 0; j < 8; ++j)
            v[j] = f32_to_bf16_rne(s[g * 8 + j][oo]);
        *(us8_t*)&wTe[(size_t)(o0 + oo) * DIM + d0 + g * 8] = v;
    }
}

// ---------------------------------------------------------------------------
// Pass 2: grouped GEMM, 256x256 tile, BK=64, 8 waves (2Mx4N), 8-phase
// schedule with counted vmcnt (T3+T4), setprio (T5), XCD swizzle (T1).
//
// LDS swizzle (T2), 3-bit: phys = logical ^ (bit7->bit4) ^ (bit8->bit5)
//                                         ^ (bit9->bit6).
// Row stride is 128B, so row bits 0,1,2 (byte bits 7,8,9) are XORed into
// the 16B-slot index (byte bits 4,5,6). Within ANY 8-consecutive-lane
// group of a ds_read_b128 (fq fixed, fr = lane&7 varying) the slot index
// {fq0^fr0, fq1^fr1, fr2 (^ks)} covers all 8 slots exactly once -> one
// clean 32-bank sweep per group; also 8-slots x2 per 16-lane group and
// 8/bank per full wave. Conflict-free under group-of-8 / quarter-wave /
// full-wave service models. (Round-2 post-mortem: full-wave balance alone
// left a constant 4.0 extra cyc per ds_read_b128 across 3 layouts.)
// global_load_lds writes linearly -> inverse-swizzle the per-lane GLOBAL
// source address; ds_read applies the same XOR (rule 21, involution:
// target bits 4-6 don't overlap source bits 7-9).
//
// Fragment reads hoisted (m201 pattern): each A/B half ds_read ONCE per
// K-tile, held in registers across its two consuming phases:
//   p0: load af0(8)+bf0(4) -> mfma(af0,bf0)
//   p1: load bf1(4)        -> mfma(af0,bf1)
//   p2: load af1(8)        -> mfma(af1,bf0)
//   p3: (none)             -> mfma(af1,bf1)
//
// Staging/vmcnt schedule unchanged (passed refcheck rounds 1-2).
// ---------------------------------------------------------------------------
__device__ __forceinline__ void async_copy16(const uint16_t* g, uint16_t* l) {
    __builtin_amdgcn_global_load_lds((const GLOBAL_AS void*)g,
                                     (LDS_AS void*)l, 16, 0, 0);
}

#define STAGE_A(BUF, HALF, KT) do {                                           \
    const uint16_t* _g = aSrc + (size_t)(HALF) * 128 * DIM + (KT) * 64;       \
    uint16_t* _l = aDst + (BUF) * 16384 + (HALF) * 8192;                      \
    async_copy16(_g, _l);                                                     \
    async_copy16(_g + (size_t)64 * DIM, _l + 4096);                           \
} while (0)

#define STAGE_B(BUF, HALF, KT) do {                                           \
    const uint16_t* _g = bSrc + (size_t)(HALF) * 128 * DIM + (KT) * 64;       \
    uint16_t* _l = bDst + (BUF) * 16384 + (HALF) * 8192;                      \
    async_copy16(_g, _l);                                                     \
    async_copy16(_g + (size_t)64 * DIM, _l + 4096);                           \
} while (0)

// ds_read one A half (8 x b128) into dst[4][2]
#define LOAD_A(dst, BUF, MH) do {                                             \
    const uint16_t* _p = smem + (BUF) * 16384 + (MH) * 8192;                  \
    _Pragma("unroll") for (int mi = 0; mi < 4; ++mi) {                        \
        const uint16_t* _r = _p + (wm * 64 + mi * 16 + fr) * 64;              \
        dst[mi][0] = *(const bf8_t*)(_r + colk0);                             \
        dst[mi][1] = *(const bf8_t*)(_r + colk1);                             \
    }                                                                         \
} while (0)

// ds_read one B half (4 x b128) into dst[2][2]
#define LOAD_B(dst, BUF, NH) do {                                             \
    const uint16_t* _p = smem + 32768 + (BUF) * 16384 + (NH) * 8192;          \
    _Pragma("unroll") for (int ni = 0; ni < 2; ++ni) {                        \
        const uint16_t* _r = _p + (wn * 32 + ni * 16 + fr) * 64;              \
        dst[ni][0] = *(const bf8_t*)(_r + colk0);                             \
        dst[ni][1] = *(const bf8_t*)(_r + colk1);                             \
    }                                                                         \
} while (0)

#define PHASE_CORE(AF, BF, MH, NH, STAGE_CODE, TAIL_CODE) do {                \
    STAGE_CODE                                                                \
    __builtin_amdgcn_s_barrier();                                             \
    asm volatile("s_waitcnt lgkmcnt(0)" ::: "memory");                        \
    __builtin_amdgcn_sched_barrier(0);                                        \
    __builtin_amdgcn_s_setprio(1);                                            \
    _Pragma("unroll") for (int ks = 0; ks < 2; ++ks)                          \
        _Pragma("unroll") for (int mi = 0; mi < 4; ++mi)                      \
            _Pragma("unroll") for (int ni = 0; ni < 2; ++ni)                  \
                acc[MH][NH][mi][ni] = __builtin_amdgcn_mfma_f32_16x16x32_bf16(\
                    AF[mi][ks], BF[ni][ks], acc[MH][NH][mi][ni], 0, 0, 0);    \
    __builtin_amdgcn_s_setprio(0);                                            \
    TAIL_CODE                                                                 \
    __builtin_amdgcn_s_barrier();                                             \
} while (0)

__global__ void __launch_bounds__(512, 2)
grouped_gemm_kernel(const uint16_t* __restrict__ A,
                    const uint16_t* __restrict__ BT,
                    const int* __restrict__ gsize,
                    float* __restrict__ C) {
    __shared__ __align__(16) uint16_t smem[65536];   // 128 KiB

    // T1: XCD-aware swizzle. nwg = 1024 = 8 XCDs x 128.
    const int bid = blockIdx.x;
    const int wg  = (bid & 7) * 128 + (bid >> 3);
    const int tile_m = wg >> 3;           // 0..127
    const int tile_n = wg & 7;            // 0..7
    const int row0 = tile_m * BM;
    const int col0 = tile_n * BN;

    // Expert lookup (groups are multiples of BM=256: tiles never straddle).
    int e = 0, base = 0;
#pragma unroll
    for (int i = 0; i < NEXP; ++i) {
        int nx = base + gsize[i];
        if (row0 >= nx) { base = nx; e = i + 1; }
    }
    const uint16_t* Be = BT + (size_t)e * (size_t)ODIM * DIM;

    const int tid  = threadIdx.x;
    const int lane = tid & 63;
    const int wave = tid >> 6;   // 0..7
    const int wm   = wave >> 2;  // 0..1 (M)
    const int wn   = wave & 3;   // 0..3 (N)
    const int fr   = lane & 15;
    const int fq   = lane >> 4;

    // --- staging: linear LDS dest byte d0 -> inverse-swizzled logical
    //     (row,col); the global source gets the swizzle (rule 21).
    //     d0b bits 7,8,9 = lane bits 3,4,5.
    const int d0b = wave * 1024 + lane * 16;
    const int l0  = d0b ^ (((d0b >> 7) & 1) << 4)
                        ^ (((d0b >> 8) & 1) << 5)
                        ^ (((d0b >> 9) & 1) << 6);
    const int srow = l0 >> 7;            // 0..63 (issue 1 adds 64)
    const int scol = (l0 & 127) >> 1;    // element 0..63
    const uint16_t* aSrc = A  + (size_t)(row0 + srow) * DIM + scol;
    const uint16_t* bSrc = Be + (size_t)(col0 + srow) * DIM + scol;
    uint16_t* const aDst = smem + wave * 512;            // HW adds lane*16B
    uint16_t* const bDst = smem + 32768 + wave * 512;

    // --- fragment read column offsets (elements), 3-bit XOR swizzle:
    //     row bits 0,1,2 == fr bits 0,1,2 (mi*16/ni*16 only touch row>=4,
    //     wm*64/wn*32 higher) -> elem XOR (fr&7)<<3 = byte bits 7,8,9->4,5,6.
    const int xorel = (fr & 7) << 3;
    const int colk0 = (fq * 8) ^ xorel;
    const int colk1 = (fq * 8) ^ 32 ^ xorel;

    f4_t acc[2][2][4][2] = {};   // [mh][nh][mi][ni]

    // Prologue: tile0 fully + tile1's h0; vmcnt(4) leaves tile1-h0 in flight.
    STAGE_A(0, 0, 0); STAGE_A(0, 1, 0); STAGE_B(0, 0, 0); STAGE_B(0, 1, 0);
    STAGE_A(1, 0, 1); STAGE_B(1, 0, 1);
    asm volatile("s_waitcnt vmcnt(4)" ::: "memory");
    __builtin_amdgcn_s_barrier();

#pragma unroll 1
    for (int j = 0; j < NT; j += 2) {
        bf8_t af0[4][2], af1[4][2], bf0[2][2], bf1[2][2];
        // ---- tile j (buf 0)
        LOAD_A(af0, 0, 0); LOAD_B(bf0, 0, 0);
        PHASE_CORE(af0, bf0, 0, 0,
                   { STAGE_A(1, 1, j + 1); STAGE_B(1, 1, j + 1); }, {});
        LOAD_B(bf1, 0, 1);
        PHASE_CORE(af0, bf1, 0, 1, {}, {});
        LOAD_A(af1, 0, 1);
        PHASE_CORE(af1, bf0, 1, 0, { if (j + 2 < NT) STAGE_A(0, 0, j + 2); }, {});
        PHASE_CORE(af1, bf1, 1, 1, { if (j + 2 < NT) STAGE_B(0, 0, j + 2); },
              { if (j + 2 < NT) asm volatile("s_waitcnt vmcnt(4)" ::: "memory");
                else            asm volatile("s_waitcnt vmcnt(0)" ::: "memory"); });
        // ---- tile j+1 (buf 1)
        LOAD_A(af0, 1, 0); LOAD_B(bf0, 1, 0);
        PHASE_CORE(af0, bf0, 0, 0,
                   { if (j + 2 < NT) { STAGE_A(0, 1, j + 2); STAGE_B(0, 1, j + 2); } }, {});
        LOAD_B(bf1, 1, 1);
        PHASE_CORE(af0, bf1, 0, 1, {}, {});
        LOAD_A(af1, 1, 1);
        PHASE_CORE(af1, bf0, 1, 0, { if (j + 3 < NT) STAGE_A(1, 0, j + 3); }, {});
        PHASE_CORE(af1, bf1, 1, 1, { if (j + 3 < NT) STAGE_B(1, 0, j + 3); },
              { if (j + 3 < NT) asm volatile("s_waitcnt vmcnt(4)" ::: "memory");
                else            asm volatile("s_waitcnt vmcnt(0)" ::: "memory"); });
    }

    // Epilogue: C/D layout col=lane&15, row=(lane>>4)*4+reg [m89/m91]
    float* Cb = C + (size_t)(row0 + wm * 64 + fq * 4) * ODIM
                  + (col0 + wn * 32 + fr);
#pragma unroll
    for (int mh = 0; mh < 2; ++mh)
#pragma unroll
        for (int nh = 0; nh < 2; ++nh)
#pragma unroll
            for (int mi = 0; mi < 4; ++mi)
#pragma unroll
                for (int ni = 0; ni < 2; ++ni)
#pragma unroll
                    for (int r = 0; r < 4; ++r)
                        Cb[(size_t)(mh * 128 + mi * 16 + r) * ODIM
                           + nh * 128 + ni * 16] = acc[mh][nh][mi][ni][r];
}

// ---------------------------------------------------------------------------
extern "C" void kernel_launch(void* const* d_in, const int* in_sizes, int n_in,
                              void* d_out, int out_size, void* d_ws, size_t ws_size,
                              hipStream_t stream) {
    const float* x  = (const float*)d_in[0];
    const float* w  = (const float*)d_in[1];
    const int*   gs = (const int*)d_in[2];
    float* out = (float*)d_out;

    // workspace: xb (N*K bf16, 128MB) | wT (E*O*K bf16, 128MB)
    uint16_t* xb = (uint16_t*)d_ws;
    uint16_t* wT = xb + (size_t)N_TOK * DIM;

    int n8 = N_TOK * DIM / 8;
    cvt_x_kernel<<<4096, 256, 0, stream>>>(x, xb, n8);

    dim3 tg(ODIM / 64, DIM / 64, NEXP);
    cvt_wT_kernel<<<tg, 256, 0, stream>>>(w, wT);

    grouped_gemm_kernel<<<dim3((ODIM / BN) * (N_TOK / BM)), 512, 0, stream>>>(
        xb, wT, gs, out);
}